// Round 8
// baseline (835.542 us; speedup 1.0000x reference)
//
#include <hip/hip_runtime.h>

typedef __bf16 bf16_t;
typedef __bf16 bf16x8 __attribute__((ext_vector_type(8)));
typedef __bf16 bf16x4 __attribute__((ext_vector_type(4)));
typedef float f32x4 __attribute__((ext_vector_type(4)));
typedef unsigned int u32x4 __attribute__((ext_vector_type(4)));

#define B_ 4
#define N_ 2048
#define D_ 1024
#define H_ 8
#define NB_ 4
#define M_ (B_*N_)      // 8192 rows
#define QN_ 3072        // pruned qkv cols: q(1024) k(1024) v(1024)
#define QKN_ 2048       // q,k packed row stride

__device__ __forceinline__ void async_copy16(const void* gsrc, void* ldst) {
    __builtin_amdgcn_global_load_lds(
        (const __attribute__((address_space(1))) void*)gsrc,
        (__attribute__((address_space(3))) void*)ldst, 16, 0, 0);
}

// ---------------- workspace layout (bytes) ----------------
static constexpr size_t WT_OFF  = 0;                               // bf16 (NB,3072,1024)
static constexpr size_t WT_SZ   = (size_t)NB_*QN_*D_*2;
static constexpr size_t OWT_OFF = WT_OFF + WT_SZ;                  // bf16 (NB,1024,1024)
static constexpr size_t OWT_SZ  = (size_t)NB_*D_*D_*2;
static constexpr size_t XN_OFF  = OWT_OFF + OWT_SZ;                // bf16 (8192,1024)
static constexpr size_t XN_SZ   = (size_t)M_*D_*2;
static constexpr size_t QK_OFF  = XN_OFF + XN_SZ;                  // bf16 (8192,2048)  q|k  (q pre-scaled by 1/sqrt(A))
static constexpr size_t QK_SZ   = (size_t)M_*QKN_*2;
static constexpr size_t VT_OFF  = QK_OFF + QK_SZ;                  // bf16 (32,128,2048) v transposed, m-permuted
static constexpr size_t VT_SZ   = (size_t)32*128*N_*2;
static constexpr size_t ATT_OFF = VT_OFF + VT_SZ;                  // bf16 (8192,1024)
static constexpr size_t ATT_SZ  = (size_t)M_*D_*2;
static constexpr size_t QBR_OFF = ATT_OFF + ATT_SZ;                // f32 (NB,3072)
static constexpr size_t QBR_SZ  = (size_t)NB_*QN_*4;
static constexpr size_t VS_OFF  = QBR_OFF + QBR_SZ;                // f32 (NB,32,128)  per-layer vsum (atomic)
static constexpr size_t VS_SZ   = (size_t)NB_*32*128*4;
static constexpr size_t MASK_OFF = VS_OFF + VS_SZ;                 // u16 (4,2048) AND-mask, VT-permuted order

// ---------------- weight repack: qkv_w (NB,1024,4096) -> WT (NB,3072,1024) bf16, transposed, pruned ----------------
__global__ __launch_bounds__(256) void repack_qkvw(const float* __restrict__ qw, bf16_t* __restrict__ wt)
{
    __shared__ float tile[64][65];
    const int nb = blockIdx.z;
    const int j0 = blockIdx.x * 64, d0 = blockIdx.y * 64;
    const int tx = threadIdx.x, ty = threadIdx.y;
    const float* src = qw + (size_t)nb * D_ * 4096;
    const int jj = j0 + tx;
    const int sel = jj >> 10, rr = jj & 1023, hh = rr >> 7, aa = rr & 127;
    const int orig = hh * 512 + sel * 128 + aa;   // q:[0,128) k:[128,256) v:[256,384) per head
#pragma unroll
    for (int it = 0; it < 16; ++it) {
        int dr = it * 4 + ty;
        tile[dr][tx] = src[(size_t)(d0 + dr) * 4096 + orig];
    }
    __syncthreads();
    bf16_t* dst = wt + (size_t)nb * QN_ * D_;
#pragma unroll
    for (int it = 0; it < 16; ++it) {
        int jr = it * 4 + ty;
        dst[(size_t)(j0 + jr) * D_ + d0 + tx] = (bf16_t)tile[tx][jr];
    }
}

__global__ __launch_bounds__(256) void repack_outw(const float* __restrict__ ow, bf16_t* __restrict__ owt)
{
    __shared__ float tile[64][65];
    const int nb = blockIdx.z;
    const int j0 = blockIdx.x * 64, d0 = blockIdx.y * 64;
    const int tx = threadIdx.x, ty = threadIdx.y;
    const float* src = ow + (size_t)nb * D_ * D_;
#pragma unroll
    for (int it = 0; it < 16; ++it) {
        int dr = it * 4 + ty;
        tile[dr][tx] = src[(size_t)(d0 + dr) * D_ + j0 + tx];
    }
    __syncthreads();
    bf16_t* dst = owt + (size_t)nb * D_ * D_;
#pragma unroll
    for (int it = 0; it < 16; ++it) {
        int jr = it * 4 + ty;
        dst[(size_t)(j0 + jr) * D_ + d0 + tx] = (bf16_t)tile[tx][jr];
    }
}

__global__ __launch_bounds__(256) void repack_qb(const float* __restrict__ qb, float* __restrict__ qbr)
{
    int idx = blockIdx.x * 256 + threadIdx.x;   // < NB*3072
    int nb = idx / QN_, jj = idx % QN_;
    int sel = jj >> 10, rr = jj & 1023, hh = rr >> 7, aa = rr & 127;
    qbr[idx] = qb[nb * 4096 + hh * 512 + sel * 128 + aa];
}

// ---------------- AND-mask in VT-permuted k-order + zero the per-layer vsum slabs ----------------
__global__ __launch_bounds__(256) void mask_kernel(const int* __restrict__ past_ids, unsigned short* __restrict__ maskA,
                                                   float* __restrict__ vsl)
{
    const int idx = blockIdx.x * 256 + threadIdx.x;   // < 8192
    vsl[idx] = 0.f; vsl[idx + 8192] = 0.f;            // NB*4096 = 16384 floats
    const int b = idx >> 11, P = idx & 2047;
    const int k = P & 31;
    const int m = (P & ~31) | (((k >> 2) & 1) << 4) | (((k >> 3) & 3) << 2) | (k & 3);
    maskA[idx] = past_ids[b * N_ + m] != 0 ? 0xFFFFu : 0u;
}

// ---------------- LayerNorm: x fp32 (8192,1024) -> xn bf16 ----------------
__global__ __launch_bounds__(256) void ln_kernel(const float* __restrict__ x, const float* __restrict__ g,
                                                 const float* __restrict__ bb, bf16_t* __restrict__ xn)
{
    const int row = blockIdx.x, tid = threadIdx.x;
    const float4 v = ((const float4*)(x + (size_t)row * D_))[tid];
    float s = v.x + v.y + v.z + v.w;
    float q = v.x * v.x + v.y * v.y + v.z * v.z + v.w * v.w;
#pragma unroll
    for (int d = 32; d >= 1; d >>= 1) { s += __shfl_xor(s, d); q += __shfl_xor(q, d); }
    __shared__ float ls[4], lq[4];
    if ((tid & 63) == 0) { ls[tid >> 6] = s; lq[tid >> 6] = q; }
    __syncthreads();
    s = ls[0] + ls[1] + ls[2] + ls[3];
    q = lq[0] + lq[1] + lq[2] + lq[3];
    const float mean = s * (1.f / 1024.f);
    const float var  = q * (1.f / 1024.f) - mean * mean;
    const float inv  = rsqrtf(var + 1e-5f);
    const float4 gg = ((const float4*)g)[tid];
    const float4 bv = ((const float4*)bb)[tid];
    bf16x4 o;
    o[0] = (bf16_t)((v.x - mean) * inv * gg.x + bv.x);
    o[1] = (bf16_t)((v.y - mean) * inv * gg.y + bv.y);
    o[2] = (bf16_t)((v.z - mean) * inv * gg.z + bv.z);
    o[3] = (bf16_t)((v.w - mean) * inv * gg.w + bv.w);
    *(bf16x4*)(xn + (size_t)row * D_ + tid * 4) = o;
}

// ---------------- QKV GEMM: 256x192 tile, 8 waves (2x4), BK=64, ring-2 depth-1, 1 barrier/K-step ----------------
// Grid 16x32 = 512 blocks = exactly 2 generations at 1 block/CU. 16 K-steps (half the barrier convoy
// of BK=32 ring-4). Uniform staging: 7 loads/wave (A: 4 of 32 flat-chunks, B: 3 of 24).
// LDS layout per slot: [half(k32)][chunk16][16x32 swizzled] -> per-chunk swizzle identical to proven kernel.
// Epilogue: i-outer/j-inner (full-line QK writes); fused vsum via ps[3] + quad-reduce + atomicAdd.
__global__ __launch_bounds__(512, 2) void gemm_qkv(const bf16_t* __restrict__ Am, const bf16_t* __restrict__ Bt,
                                                   const float* __restrict__ bias,
                                                   bf16_t* __restrict__ outQK, bf16_t* __restrict__ vtOut,
                                                   float* __restrict__ vsOut)
{
    __shared__ bf16_t As[2 * 16384];   // 64KB: 2 slots x (256 rows x 64 k)
    __shared__ bf16_t Bs[2 * 12288];   // 48KB: 2 slots x (192 rows x 64 k)
    const int tid = threadIdx.x;
    const int lane = tid & 63, wave = tid >> 6;
    const int wr = wave >> 2, wc = wave & 3;        // 2 x 4 wave grid, wave tile 128x48
    const int quad = lane >> 4, l15 = lane & 15;
    const int swz = quad ^ ((l15 >> 1) & 3);                  // read-side chunk swizzle
    const int slane8 = ((lane & 3) ^ ((lane >> 3) & 3)) * 8;  // staging source col perm
    const int lrow = lane >> 2;
    const int m0 = blockIdx.y * 256, n0 = blockIdx.x * 192;
    const int Kn = D_;

    // staging assignment (flat chunk = ch*2 + half): wave stages A {4w..4w+3}, B {3w..3w+2}
    const bf16_t* gA[4]; bf16_t* dA[4];
    const bf16_t* gB[3]; bf16_t* dB[3];
#pragma unroll
    for (int u = 0; u < 4; ++u) {
        const int a = wave * 4 + u, ch = a >> 1, hf = a & 1;
        gA[u] = Am + (size_t)(m0 + ch * 16 + lrow) * Kn + hf * 32 + slane8;
        dA[u] = &As[hf * 8192 + ch * 512 + lane * 8];
    }
#pragma unroll
    for (int u = 0; u < 3; ++u) {
        const int b = wave * 3 + u, ch = b >> 1, hf = b & 1;
        gB[u] = Bt + (size_t)(n0 + ch * 16 + lrow) * Kn + hf * 32 + slane8;
        dB[u] = &Bs[hf * 6144 + ch * 512 + lane * 8];
    }

    auto STAGE = [&](int slot) {
#pragma unroll
        for (int u = 0; u < 4; ++u) { async_copy16(gA[u], dA[u] + slot * 16384); gA[u] += 64; }
#pragma unroll
        for (int u = 0; u < 3; ++u) { async_copy16(gB[u], dB[u] + slot * 12288); gB[u] += 64; }
    };

    f32x4 acc[8][3] = {};
    const int NT = Kn >> 6;   // 16

    STAGE(0);
    asm volatile("s_waitcnt vmcnt(0)" ::: "memory");
    __builtin_amdgcn_s_barrier();

    const int abase = wr * 4096 + l15 * 32 + swz * 8;   // + hf*8192 + i*512
    const int bbase = wc * 1536 + l15 * 32 + swz * 8;   // + hf*6144 + j*512

    for (int t = 0; t < NT; ++t) {
        const int slot = t & 1;
        const bf16_t* ra = &As[slot * 16384 + abase];
        const bf16_t* rb = &Bs[slot * 12288 + bbase];
        if (t + 1 < NT) STAGE(slot ^ 1);    // issue-early: 7 loads in flight across whole step
        __builtin_amdgcn_s_setprio(1);
#pragma unroll
        for (int hf = 0; hf < 2; ++hf) {
            bf16x8 af[8], bfv[3];
#pragma unroll
            for (int j = 0; j < 3; ++j) bfv[j] = *(const bf16x8*)(rb + hf * 6144 + j * 512);
#pragma unroll
            for (int i = 0; i < 8; ++i) af[i] = *(const bf16x8*)(ra + hf * 8192 + i * 512);
#pragma unroll
            for (int i = 0; i < 8; ++i)
#pragma unroll
                for (int j = 0; j < 3; ++j)
                    acc[i][j] = __builtin_amdgcn_mfma_f32_16x16x32_bf16(af[i], bfv[j], acc[i][j], 0, 0, 0);
        }
        __builtin_amdgcn_s_setprio(0);
        if (t + 1 < NT) asm volatile("s_waitcnt vmcnt(0)" ::: "memory");   // next slot landed
        __builtin_amdgcn_s_barrier();
    }

    // epilogue: i-outer/j-inner (48 contiguous cols per row close in time -> full-line writes)
    const int bb2 = m0 >> 11;   // block lies in one batch
    int colgj[3]; float bvj[3];
#pragma unroll
    for (int j = 0; j < 3; ++j) { colgj[j] = n0 + wc * 48 + j * 16 + l15; bvj[j] = bias[colgj[j]]; }
    float ps[3] = {0.f, 0.f, 0.f};
#pragma unroll
    for (int i = 0; i < 8; ++i) {
        const int rowg = m0 + wr * 128 + i * 16 + quad * 4;   // r=0 base; 4 consecutive rows
        const int mloc = rowg & 2047;
        const int mperm = (mloc & ~31) | (((mloc >> 2) & 3) << 3) | (((mloc >> 4) & 1) << 2);
#pragma unroll
        for (int j = 0; j < 3; ++j) {
            const int colg = colgj[j];
            const float bv = bvj[j];
            if (colg >= 2048) {
                // V: write transposed VT[(b*8+h)*128 + l][mperm]; accumulate vsum partial
                const int hh = (colg - 2048) >> 7, ll = (colg - 2048) & 127;
                bf16x4 sv;
#pragma unroll
                for (int r = 0; r < 4; ++r) { sv[r] = (bf16_t)(acc[i][j][r] + bv); ps[j] += acc[i][j][r]; }
                *(bf16x4*)(vtOut + ((size_t)(bb2 * 8 + hh) * 128 + ll) * (size_t)N_ + mperm) = sv;
            } else {
                const float qs = (colg < 1024) ? 0.08838834764831845f : 1.f;   // pre-scale q by 1/sqrt(A)
#pragma unroll
                for (int r = 0; r < 4; ++r)
                    outQK[(size_t)(rowg + r) * QKN_ + colg] = (bf16_t)((acc[i][j][r] + bv) * qs);
            }
        }
    }
#pragma unroll
    for (int j = 0; j < 3; ++j) {
        const int colg = colgj[j];
        if (colg >= 2048) {
            const int hh = (colg - 2048) >> 7, ll = (colg - 2048) & 127;
            float p = ps[j] + 32.f * bvj[j];   // this lane covered 32 rows
            p += __shfl_xor(p, 16);
            p += __shfl_xor(p, 32);
            if (quad == 0) atomicAdd(&vsOut[(size_t)(bb2 * 8 + hh) * 128 + ll], p);
        }
    }
}

// ---------------- out-proj GEMM (unchanged control): 256x128 tile, ring-4, single barrier/K-step ----------------
// Grid 8x32 = 256 blocks = exactly 1 generation. x_out = resid_in + A@W + bias.
__global__ __launch_bounds__(512, 2) void gemm_out(const bf16_t* __restrict__ Am, const bf16_t* __restrict__ Bt,
                                                   const float* __restrict__ bias,
                                                   const float* __restrict__ resid_in, float* __restrict__ resid_out)
{
    __shared__ bf16_t As[4 * 256 * 32];
    __shared__ bf16_t Bs[4 * 128 * 32];
    const int tid = threadIdx.x;
    const int lane = tid & 63, wave = tid >> 6;
    const int wr = wave >> 2, wc = wave & 3;
    const int quad = lane >> 4, l15 = lane & 15;
    const int swz = quad ^ ((l15 >> 1) & 3);
    const int slane8 = ((lane & 3) ^ ((lane >> 3) & 3)) * 8;
    const int lrow = lane >> 2;
    const int m0 = blockIdx.y * 256, n0 = blockIdx.x * 128;
    const int Kn = D_;

    const int chA0 = wave * 2, chA1 = chA0 + 1;
    const bf16_t* gA0 = Am + (size_t)(m0 + chA0 * 16 + lrow) * Kn + slane8;
    const bf16_t* gA1 = Am + (size_t)(m0 + chA1 * 16 + lrow) * Kn + slane8;
    const bf16_t* gB  = Bt + (size_t)(n0 + wave * 16 + lrow) * Kn + slane8;
    bf16_t* const dA0 = &As[chA0 * 512 + lane * 8];
    bf16_t* const dA1 = &As[chA1 * 512 + lane * 8];
    bf16_t* const dB  = &Bs[wave * 512 + lane * 8];

    auto STAGE = [&](int slot) {
        async_copy16(gA0, dA0 + slot * 8192);
        async_copy16(gA1, dA1 + slot * 8192);
        async_copy16(gB,  dB  + slot * 4096);
        gA0 += 32; gA1 += 32; gB += 32;
    };

    f32x4 acc[8][2] = {};
    const int NT = Kn >> 5;

    STAGE(0); STAGE(1); STAGE(2);
    asm volatile("s_waitcnt vmcnt(6)" ::: "memory");
    __builtin_amdgcn_s_barrier();

    const int aoff = (wr * 128 + l15) * 32 + swz * 8;
    const int boff = (wc * 32  + l15) * 32 + swz * 8;

    for (int t = 0; t < NT; ++t) {
        const int ring = t & 3;
        const bf16_t* ra = &As[ring * 8192 + aoff];
        const bf16_t* rb = &Bs[ring * 4096 + boff];
        bf16x8 af[8], bfv[2];
#pragma unroll
        for (int j = 0; j < 2; ++j) bfv[j] = *(const bf16x8*)(rb + j * 512);
#pragma unroll
        for (int i = 0; i < 8; ++i) af[i] = *(const bf16x8*)(ra + i * 512);
        if (t + 3 < NT) STAGE((t + 3) & 3);
        __builtin_amdgcn_s_setprio(1);
#pragma unroll
        for (int i = 0; i < 8; ++i)
#pragma unroll
            for (int j = 0; j < 2; ++j)
                acc[i][j] = __builtin_amdgcn_mfma_f32_16x16x32_bf16(af[i], bfv[j], acc[i][j], 0, 0, 0);
        __builtin_amdgcn_s_setprio(0);
        if (t + 3 < NT)      asm volatile("s_waitcnt vmcnt(6)" ::: "memory");
        else if (t + 2 < NT) asm volatile("s_waitcnt vmcnt(3)" ::: "memory");
        else if (t + 1 < NT) asm volatile("s_waitcnt vmcnt(0)" ::: "memory");
        __builtin_amdgcn_s_barrier();
    }

#pragma unroll
    for (int i = 0; i < 8; ++i) {
#pragma unroll
        for (int j = 0; j < 2; ++j) {
            const int colg = n0 + wc * 32 + j * 16 + l15;
            const float bv = bias[colg];
#pragma unroll
            for (int r = 0; r < 4; ++r) {
                const int rowg = m0 + wr * 128 + i * 16 + quad * 4 + r;
                const size_t off = (size_t)rowg * D_ + colg;
                resid_out[off] = resid_in[off] + acc[i][j][r] + bv;
            }
        }
    }
}

// ---------------- fused masked-silu-softmax attention (unchanged) ----------------
template<bool CAUSAL>
__device__ __forceinline__ void attn_tile(
    int m0, int m0n, int n0, int b, int h,
    const bf16_t* __restrict__ qk, const bf16_t* __restrict__ vtb,
    const unsigned short* __restrict__ maskB,
    bf16_t* Ks, bf16_t* Vs,
    const bf16x8 (&qf)[2][4], bf16x8 onesf,
    f32x4 (&oacc)[2][8], f32x4 (&dacc)[2])
{
    const int tid = threadIdx.x, lane = tid & 63, wave = tid >> 6;
    const int quad = lane >> 4, l15 = lane & 15;
    const int swz = quad ^ ((l15 >> 1) & 3);
    const int slane8 = ((lane & 3) ^ ((lane >> 3) & 3)) * 8;
    const int lrow = lane >> 2;
    const float invN = 1.f / 2048.f;

    // (1) issue V(m0) -> Vs ; AND-mask fragments (L2-resident 16KB) issued alongside
#pragma unroll
    for (int s = 0; s < 8; ++s) {
        const int kkc = s & 3, rg = (s >> 2) + wave * 2;
        async_copy16(vtb + (size_t)(rg * 16 + lrow) * N_ + m0 + kkc * 32 + slane8,
                     &Vs[kkc * 4096 + rg * 512 + lane * 8]);
    }
    bf16x8 mAf[4];
#pragma unroll
    for (int kk = 0; kk < 4; ++kk)
        mAf[kk] = *(const bf16x8*)(maskB + m0 + kk * 32 + quad * 8);

    // (2) S^T = K Q^T
    f32x4 sacc[2][8] = {};
    __builtin_amdgcn_s_setprio(1);
#pragma unroll
    for (int kk = 0; kk < 4; ++kk) {
#pragma unroll
        for (int j = 0; j < 8; ++j) {
            bf16x8 kf = *(const bf16x8*)&Ks[kk * 4096 + (j * 16 + l15) * 32 + swz * 8];
            sacc[0][j] = __builtin_amdgcn_mfma_f32_16x16x32_bf16(kf, qf[0][kk], sacc[0][j], 0, 0, 0);
            sacc[1][j] = __builtin_amdgcn_mfma_f32_16x16x32_bf16(kf, qf[1][kk], sacc[1][j], 0, 0, 0);
        }
    }
    __builtin_amdgcn_s_setprio(0);

    // (3) softmax -> pf A-frags in registers; e = 1 + silu(s)/N, masked via AND
    bf16x8 pf[2][4];
#pragma unroll
    for (int kk = 0; kk < 4; ++kk) {
#pragma unroll
        for (int s = 0; s < 2; ++s) {
            const int j = kk * 2 + s;
#pragma unroll
            for (int nb = 0; nb < 2; ++nb) {
#pragma unroll
                for (int r = 0; r < 4; ++r) {
                    const float sv = sacc[nb][j][r];                      // already scaled by 1/sqrt(A)
                    const float xc = __builtin_amdgcn_fmed3f(sv, -4.f, 4.f);
                    float sg = __builtin_fmaf(xc, 0.25f * invN, 0.5f * invN);
                    sg = __builtin_fmaf(-(xc * (0.03125f * invN)), fabsf(xc), sg);
                    float e = __builtin_fmaf(sv, sg, 1.f);
                    if (CAUSAL) {
                        const int dmn = (m0 + j * 16 + quad * 4 + r) - (n0 + wave * 32 + nb * 16 + l15);
                        e = (dmn > 0) ? e : 0.f;
                    }
                    pf[nb][kk][s * 4 + r] = (bf16_t)e;
                }
            }
        }
        *(u32x4*)&pf[0][kk] = *(u32x4*)&pf[0][kk] & *(const u32x4*)&mAf[kk];
        *(u32x4*)&pf[1][kk] = *(u32x4*)&pf[1][kk] & *(const u32x4*)&mAf[kk];
    }

    __syncthreads();   // V landed + visible; Ks free

    // (4) prefetch K(m0n) -> Ks
    if (m0n < N_) {
        const size_t baseq = (size_t)b * N_ * QKN_;
#pragma unroll
        for (int s = 0; s < 8; ++s) {
            const int kkc = s & 3, rg = (s >> 2) + wave * 2;
            async_copy16(qk + baseq + (size_t)(m0n + rg * 16 + lrow) * QKN_ + 1024 + h * 128 + kkc * 32 + slane8,
                         &Ks[kkc * 4096 + rg * 512 + lane * 8]);
        }
    }

    // (5) O += P V ; den += P ones  (pf already masked -> den correct)
    __builtin_amdgcn_s_setprio(1);
#pragma unroll
    for (int kk = 0; kk < 4; ++kk) {
        dacc[0] = __builtin_amdgcn_mfma_f32_16x16x32_bf16(pf[0][kk], onesf, dacc[0], 0, 0, 0);
        dacc[1] = __builtin_amdgcn_mfma_f32_16x16x32_bf16(pf[1][kk], onesf, dacc[1], 0, 0, 0);
#pragma unroll
        for (int j = 0; j < 8; ++j) {
            bf16x8 vf = *(const bf16x8*)&Vs[kk * 4096 + (j * 16 + l15) * 32 + swz * 8];
            oacc[0][j] = __builtin_amdgcn_mfma_f32_16x16x32_bf16(pf[0][kk], vf, oacc[0][j], 0, 0, 0);
            oacc[1][j] = __builtin_amdgcn_mfma_f32_16x16x32_bf16(pf[1][kk], vf, oacc[1][j], 0, 0, 0);
        }
    }
    __builtin_amdgcn_s_setprio(0);
    __syncthreads();   // K(m0n) landed + visible; Vs free
}

__global__ __launch_bounds__(256, 2) void attn_kernel(const bf16_t* __restrict__ qk, const bf16_t* __restrict__ vt,
                                                      const int* __restrict__ past_ids, const float* __restrict__ vsum,
                                                      const unsigned short* __restrict__ maskA,
                                                      bf16_t* __restrict__ att)
{
    __shared__ bf16_t Ks[4 * 128 * 32];
    __shared__ bf16_t Vs[4 * 128 * 32];

    const int bx = blockIdx.x;
    const int bh = bx & 31, g = bx >> 5;
    const int t = (g < 8) ? g : 23 - g;          // CU co-resident pair (g,g+8) -> tiles sum 17
    const int b = bh >> 3, h = bh & 7;
    const int n0 = t << 7;
    const int tid = threadIdx.x, lane = tid & 63, wave = tid >> 6;
    const int quad = lane >> 4, l15 = lane & 15;
    const int slane8 = ((lane & 3) ^ ((lane >> 3) & 3)) * 8;
    const int lrow = lane >> 2;
    const bf16_t* vtb = vt + (size_t)bh * 128 * N_;
    const unsigned short* maskB = maskA + b * N_;
    const float invN = 1.f / 2048.f;

    // Q B-frags resident in VGPRs (2 n16-blocks per wave)
    bf16x8 qf[2][4];
#pragma unroll
    for (int nb = 0; nb < 2; ++nb) {
        const bf16_t* gq = qk + (size_t)b * N_ * QKN_ + (size_t)(n0 + wave * 32 + nb * 16 + l15) * QKN_ + h * 128 + quad * 8;
#pragma unroll
        for (int kk = 0; kk < 4; ++kk) qf[nb][kk] = *(const bf16x8*)(gq + kk * 32);
    }
    const float vnf0 = past_ids[b * N_ + n0 + wave * 32 + l15] != 0 ? 1.f : 0.f;
    const float vnf1 = past_ids[b * N_ + n0 + wave * 32 + 16 + l15] != 0 ? 1.f : 0.f;
    bf16x8 onesf;
#pragma unroll
    for (int i = 0; i < 8; ++i) onesf[i] = (bf16_t)1.f;

    // prologue: stage K(first tile)
    {
        const size_t baseq = (size_t)b * N_ * QKN_;
#pragma unroll
        for (int s = 0; s < 8; ++s) {
            const int kkc = s & 3, rg = (s >> 2) + wave * 2;
            async_copy16(qk + baseq + (size_t)(n0 + rg * 16 + lrow) * QKN_ + 1024 + h * 128 + kkc * 32 + slane8,
                         &Ks[kkc * 4096 + rg * 512 + lane * 8]);
        }
    }
    __syncthreads();

    f32x4 oacc[2][8] = {};
    f32x4 dacc[2] = {};

    attn_tile<true>(n0, n0 + 128, n0, b, h, qk, vtb, maskB, Ks, Vs, qf, onesf, oacc, dacc);
    for (int m0 = n0 + 128; m0 < N_; m0 += 128)
        attn_tile<false>(m0, m0 + 128, n0, b, h, qk, vtb, maskB, Ks, Vs, qf, onesf, oacc, dacc);

    // epilogue: rows n = quad*4+r (+nb*16), cols j*16+l15 ; invalid n or empty den -> uniform mean(V)
    float vsr[8];
#pragma unroll
    for (int j = 0; j < 8; ++j) vsr[j] = vsum[bh * 128 + j * 16 + l15];
#pragma unroll
    for (int nb = 0; nb < 2; ++nb) {
        const float vn = nb ? vnf1 : vnf0;
#pragma unroll
        for (int r = 0; r < 4; ++r) {
            const float dn = dacc[nb][r];
            const bool uni = (vn == 0.f) || !(dn > 0.f);
            const float rc = uni ? 0.f : __builtin_amdgcn_rcpf(dn);
            const int gn = n0 + wave * 32 + nb * 16 + quad * 4 + r;
#pragma unroll
            for (int j = 0; j < 8; ++j) {
                const float ov = uni ? (vsr[j] * invN) : (oacc[nb][j][r] * rc);
                att[(size_t)(b * N_ + gn) * 1024 + h * 128 + j * 16 + l15] = (bf16_t)ov;
            }
        }
    }
}

extern "C" void kernel_launch(void* const* d_in, const int* in_sizes, int n_in,
                              void* d_out, int out_size, void* d_ws, size_t ws_size,
                              hipStream_t stream) {
    (void)in_sizes; (void)n_in; (void)out_size; (void)ws_size;
    const int*   past_ids = (const int*)d_in[1];
    const float* past_emb = (const float*)d_in[2];
    const float* qkv_w    = (const float*)d_in[3];
    const float* qkv_b    = (const float*)d_in[4];
    const float* out_w    = (const float*)d_in[5];
    const float* out_b    = (const float*)d_in[6];
    const float* ln_g     = (const float*)d_in[7];
    const float* ln_b     = (const float*)d_in[8];

    float* x = (float*)d_out;
    char* ws = (char*)d_ws;
    bf16_t* WT  = (bf16_t*)(ws + WT_OFF);
    bf16_t* OWT = (bf16_t*)(ws + OWT_OFF);
    bf16_t* XN  = (bf16_t*)(ws + XN_OFF);
    bf16_t* QK  = (bf16_t*)(ws + QK_OFF);
    bf16_t* VT  = (bf16_t*)(ws + VT_OFF);
    bf16_t* ATT = (bf16_t*)(ws + ATT_OFF);
    float*  QBR = (float*)(ws + QBR_OFF);
    float*  VSL = (float*)(ws + VS_OFF);
    unsigned short* MASKA = (unsigned short*)(ws + MASK_OFF);

    repack_qkvw<<<dim3(48, 16, NB_), dim3(64, 4), 0, stream>>>(qkv_w, WT);
    repack_outw<<<dim3(16, 16, NB_), dim3(64, 4), 0, stream>>>(out_w, OWT);
    repack_qb<<<48, 256, 0, stream>>>(qkv_b, QBR);
    mask_kernel<<<32, 256, 0, stream>>>(past_ids, MASKA, VSL);

    for (int layer = 0; layer < NB_; ++layer) {
        const float* xin = (layer == 0) ? past_emb : x;
        ln_kernel<<<M_, 256, 0, stream>>>(xin, ln_g + layer * D_, ln_b + layer * D_, XN);
        gemm_qkv<<<dim3(QN_ / 192, M_ / 256), 512, 0, stream>>>(
            XN, WT + (size_t)layer * QN_ * D_, QBR + layer * QN_, QK, VT, VSL + layer * 4096);
        attn_kernel<<<512, 256, 0, stream>>>(QK, VT, past_ids, VSL + layer * 4096, MASKA, ATT);
        gemm_out<<<dim3(D_ / 128, M_ / 256), 512, 0, stream>>>(
            ATT, OWT + (size_t)layer * D_ * D_, out_b + layer * D_, xin, x);
    }
}

// Round 9
// 821.423 us; speedup vs baseline: 1.0172x; 1.0172x over previous
//
#include <hip/hip_runtime.h>

typedef __bf16 bf16_t;
typedef __bf16 bf16x8 __attribute__((ext_vector_type(8)));
typedef __bf16 bf16x4 __attribute__((ext_vector_type(4)));
typedef float f32x4 __attribute__((ext_vector_type(4)));
typedef unsigned int u32x4 __attribute__((ext_vector_type(4)));

#define B_ 4
#define N_ 2048
#define D_ 1024
#define H_ 8
#define NB_ 4
#define M_ (B_*N_)      // 8192 rows
#define QN_ 3072        // pruned qkv cols: q(1024) k(1024) v(1024)
#define QKN_ 2048       // q,k packed row stride

__device__ __forceinline__ void async_copy16(const void* gsrc, void* ldst) {
    __builtin_amdgcn_global_load_lds(
        (const __attribute__((address_space(1))) void*)gsrc,
        (__attribute__((address_space(3))) void*)ldst, 16, 0, 0);
}

// ---------------- workspace layout (bytes) ----------------
static constexpr size_t WT_OFF  = 0;                               // bf16 (NB,3072,1024)
static constexpr size_t WT_SZ   = (size_t)NB_*QN_*D_*2;
static constexpr size_t OWT_OFF = WT_OFF + WT_SZ;                  // bf16 (NB,1024,1024)
static constexpr size_t OWT_SZ  = (size_t)NB_*D_*D_*2;
static constexpr size_t XN_OFF  = OWT_OFF + OWT_SZ;                // bf16 (8192,1024)
static constexpr size_t XN_SZ   = (size_t)M_*D_*2;
static constexpr size_t QK_OFF  = XN_OFF + XN_SZ;                  // bf16 (8192,2048)  q|k  (q pre-scaled by 1/sqrt(A))
static constexpr size_t QK_SZ   = (size_t)M_*QKN_*2;
static constexpr size_t VT_OFF  = QK_OFF + QK_SZ;                  // bf16 (32,128,2048) v transposed, m-permuted
static constexpr size_t VT_SZ   = (size_t)32*128*N_*2;
static constexpr size_t ATT_OFF = VT_OFF + VT_SZ;                  // bf16 (8192,1024)
static constexpr size_t ATT_SZ  = (size_t)M_*D_*2;
static constexpr size_t QBR_OFF = ATT_OFF + ATT_SZ;                // f32 (NB,3072)
static constexpr size_t QBR_SZ  = (size_t)NB_*QN_*4;
static constexpr size_t VS_OFF  = QBR_OFF + QBR_SZ;                // f32 (NB,32,128)  per-layer vsum (atomic)
static constexpr size_t VS_SZ   = (size_t)NB_*32*128*4;
static constexpr size_t MASK_OFF = VS_OFF + VS_SZ;                 // u16 (4,2048) AND-mask, VT-permuted order

// ---------------- weight repack: qkv_w (NB,1024,4096) -> WT (NB,3072,1024) bf16, transposed, pruned ----------------
__global__ __launch_bounds__(256) void repack_qkvw(const float* __restrict__ qw, bf16_t* __restrict__ wt)
{
    __shared__ float tile[64][65];
    const int nb = blockIdx.z;
    const int j0 = blockIdx.x * 64, d0 = blockIdx.y * 64;
    const int tx = threadIdx.x, ty = threadIdx.y;
    const float* src = qw + (size_t)nb * D_ * 4096;
    const int jj = j0 + tx;
    const int sel = jj >> 10, rr = jj & 1023, hh = rr >> 7, aa = rr & 127;
    const int orig = hh * 512 + sel * 128 + aa;   // q:[0,128) k:[128,256) v:[256,384) per head
#pragma unroll
    for (int it = 0; it < 16; ++it) {
        int dr = it * 4 + ty;
        tile[dr][tx] = src[(size_t)(d0 + dr) * 4096 + orig];
    }
    __syncthreads();
    bf16_t* dst = wt + (size_t)nb * QN_ * D_;
#pragma unroll
    for (int it = 0; it < 16; ++it) {
        int jr = it * 4 + ty;
        dst[(size_t)(j0 + jr) * D_ + d0 + tx] = (bf16_t)tile[tx][jr];
    }
}

__global__ __launch_bounds__(256) void repack_outw(const float* __restrict__ ow, bf16_t* __restrict__ owt)
{
    __shared__ float tile[64][65];
    const int nb = blockIdx.z;
    const int j0 = blockIdx.x * 64, d0 = blockIdx.y * 64;
    const int tx = threadIdx.x, ty = threadIdx.y;
    const float* src = ow + (size_t)nb * D_ * D_;
#pragma unroll
    for (int it = 0; it < 16; ++it) {
        int dr = it * 4 + ty;
        tile[dr][tx] = src[(size_t)(d0 + dr) * D_ + j0 + tx];
    }
    __syncthreads();
    bf16_t* dst = owt + (size_t)nb * D_ * D_;
#pragma unroll
    for (int it = 0; it < 16; ++it) {
        int jr = it * 4 + ty;
        dst[(size_t)(j0 + jr) * D_ + d0 + tx] = (bf16_t)tile[tx][jr];
    }
}

__global__ __launch_bounds__(256) void repack_qb(const float* __restrict__ qb, float* __restrict__ qbr)
{
    int idx = blockIdx.x * 256 + threadIdx.x;   // < NB*3072
    int nb = idx / QN_, jj = idx % QN_;
    int sel = jj >> 10, rr = jj & 1023, hh = rr >> 7, aa = rr & 127;
    qbr[idx] = qb[nb * 4096 + hh * 512 + sel * 128 + aa];
}

// ---------------- AND-mask in VT-permuted k-order + zero the per-layer vsum slabs ----------------
__global__ __launch_bounds__(256) void mask_kernel(const int* __restrict__ past_ids, unsigned short* __restrict__ maskA,
                                                   float* __restrict__ vsl)
{
    const int idx = blockIdx.x * 256 + threadIdx.x;   // < 8192
    vsl[idx] = 0.f; vsl[idx + 8192] = 0.f;            // NB*4096 = 16384 floats
    const int b = idx >> 11, P = idx & 2047;
    const int k = P & 31;
    const int m = (P & ~31) | (((k >> 2) & 1) << 4) | (((k >> 3) & 3) << 2) | (k & 3);
    maskA[idx] = past_ids[b * N_ + m] != 0 ? 0xFFFFu : 0u;
}

// ---------------- LayerNorm: x fp32 (8192,1024) -> xn bf16 ----------------
__global__ __launch_bounds__(256) void ln_kernel(const float* __restrict__ x, const float* __restrict__ g,
                                                 const float* __restrict__ bb, bf16_t* __restrict__ xn)
{
    const int row = blockIdx.x, tid = threadIdx.x;
    const float4 v = ((const float4*)(x + (size_t)row * D_))[tid];
    float s = v.x + v.y + v.z + v.w;
    float q = v.x * v.x + v.y * v.y + v.z * v.z + v.w * v.w;
#pragma unroll
    for (int d = 32; d >= 1; d >>= 1) { s += __shfl_xor(s, d); q += __shfl_xor(q, d); }
    __shared__ float ls[4], lq[4];
    if ((tid & 63) == 0) { ls[tid >> 6] = s; lq[tid >> 6] = q; }
    __syncthreads();
    s = ls[0] + ls[1] + ls[2] + ls[3];
    q = lq[0] + lq[1] + lq[2] + lq[3];
    const float mean = s * (1.f / 1024.f);
    const float var  = q * (1.f / 1024.f) - mean * mean;
    const float inv  = rsqrtf(var + 1e-5f);
    const float4 gg = ((const float4*)g)[tid];
    const float4 bv = ((const float4*)bb)[tid];
    bf16x4 o;
    o[0] = (bf16_t)((v.x - mean) * inv * gg.x + bv.x);
    o[1] = (bf16_t)((v.y - mean) * inv * gg.y + bv.y);
    o[2] = (bf16_t)((v.z - mean) * inv * gg.z + bv.z);
    o[3] = (bf16_t)((v.w - mean) * inv * gg.w + bv.w);
    *(bf16x4*)(xn + (size_t)row * D_ + tid * 4) = o;
}

// ---------------- QKV GEMM: 256x192 tile, 8 waves (2x4), BK=32, ring-4, single barrier/K-step ----------------
// Grid 16x32 = 512 blocks = exactly 2 generations at 1 block/CU. Counted vmcnt keeps 2 K-tiles in
// flight across barriers (proven 67.5 µs schedule). Epilogue: i-outer/j-inner (full-line QK writes,
// proven WRITE_SIZE fix); fused vsum via ps[3] + quad-reduce + atomicAdd.
__global__ __launch_bounds__(512, 2) void gemm_qkv(const bf16_t* __restrict__ Am, const bf16_t* __restrict__ Bt,
                                                   const float* __restrict__ bias,
                                                   bf16_t* __restrict__ outQK, bf16_t* __restrict__ vtOut,
                                                   float* __restrict__ vsOut)
{
    __shared__ bf16_t As[4 * 8192];   // 64KB: ring of 4 A K-tiles (256 rows x 32 k)
    __shared__ bf16_t Bs[4 * 6144];   // 48KB: ring of 4 B K-tiles (192 rows x 32 k)
    const int tid = threadIdx.x;
    const int lane = tid & 63, wave = tid >> 6;
    const int wr = wave >> 2, wc = wave & 3;        // 2 x 4 wave grid, wave tile 128x48
    const int quad = lane >> 4, l15 = lane & 15;
    const int swz = quad ^ ((l15 >> 1) & 3);                  // read-side chunk swizzle
    const int slane8 = ((lane & 3) ^ ((lane >> 3) & 3)) * 8;  // staging source col perm
    const int lrow = lane >> 2;
    const int m0 = blockIdx.y * 256, n0 = blockIdx.x * 192;
    const int Kn = D_;
    const bool w4 = (wave < 4);

    const int ch = wave * 2;
    const int bch0 = w4 ? 2 * wave : 4 + wave;      // 0..7 / 8..11
    const int bch1 = w4 ? 2 * wave + 1 : bch0;
    const bf16_t* gA0 = Am + (size_t)(m0 + ch * 16 + lrow) * Kn + slane8;
    const bf16_t* gA1 = gA0 + (size_t)16 * Kn;
    const bf16_t* gB0 = Bt + (size_t)(n0 + bch0 * 16 + lrow) * Kn + slane8;
    const bf16_t* gB1 = Bt + (size_t)(n0 + bch1 * 16 + lrow) * Kn + slane8;
    bf16_t* const dA0 = &As[ch * 512 + lane * 8];
    bf16_t* const dA1 = &As[(ch + 1) * 512 + lane * 8];
    bf16_t* const dB0 = &Bs[bch0 * 512 + lane * 8];
    bf16_t* const dB1 = &Bs[bch1 * 512 + lane * 8];

    auto STAGE = [&](int slot) {
        async_copy16(gA0, dA0 + slot * 8192);
        async_copy16(gA1, dA1 + slot * 8192);
        async_copy16(gB0, dB0 + slot * 6144);
        if (w4) async_copy16(gB1, dB1 + slot * 6144);
        gA0 += 32; gA1 += 32; gB0 += 32; gB1 += 32;
    };

    f32x4 acc[8][3] = {};
    const int NT = Kn >> 5;   // 32

    STAGE(0); STAGE(1); STAGE(2);
    if (w4) asm volatile("s_waitcnt vmcnt(8)" ::: "memory");
    else    asm volatile("s_waitcnt vmcnt(6)" ::: "memory");
    __builtin_amdgcn_s_barrier();

    const int aoff = wr * 4096 + l15 * 32 + swz * 8;
    const int boff = wc * 1536 + l15 * 32 + swz * 8;

    for (int t = 0; t < NT; ++t) {
        const int ring = t & 3;
        const bf16_t* ra = &As[ring * 8192 + aoff];
        const bf16_t* rb = &Bs[ring * 6144 + boff];
        bf16x8 af[8], bfv[3];
#pragma unroll
        for (int j = 0; j < 3; ++j) bfv[j] = *(const bf16x8*)(rb + j * 512);
#pragma unroll
        for (int i = 0; i < 8; ++i) af[i] = *(const bf16x8*)(ra + i * 512);
        if (t + 3 < NT) STAGE((t + 3) & 3);
        __builtin_amdgcn_s_setprio(1);
#pragma unroll
        for (int i = 0; i < 8; ++i)
#pragma unroll
            for (int j = 0; j < 3; ++j)
                acc[i][j] = __builtin_amdgcn_mfma_f32_16x16x32_bf16(af[i], bfv[j], acc[i][j], 0, 0, 0);
        __builtin_amdgcn_s_setprio(0);
        if (t + 3 < NT) {
            if (w4) asm volatile("s_waitcnt vmcnt(8)" ::: "memory");
            else    asm volatile("s_waitcnt vmcnt(6)" ::: "memory");
        } else if (t + 2 < NT) {
            if (w4) asm volatile("s_waitcnt vmcnt(4)" ::: "memory");
            else    asm volatile("s_waitcnt vmcnt(3)" ::: "memory");
        } else if (t + 1 < NT) {
            asm volatile("s_waitcnt vmcnt(0)" ::: "memory");
        }
        __builtin_amdgcn_s_barrier();
    }

    // epilogue: i-outer/j-inner (48 contiguous cols per row close in time -> full-line writes)
    const int bb2 = m0 >> 11;   // block lies in one batch
    int colgj[3]; float bvj[3];
#pragma unroll
    for (int j = 0; j < 3; ++j) { colgj[j] = n0 + wc * 48 + j * 16 + l15; bvj[j] = bias[colgj[j]]; }
    float ps[3] = {0.f, 0.f, 0.f};
#pragma unroll
    for (int i = 0; i < 8; ++i) {
        const int rowg = m0 + wr * 128 + i * 16 + quad * 4;   // r=0 base; 4 consecutive rows
        const int mloc = rowg & 2047;
        const int mperm = (mloc & ~31) | (((mloc >> 2) & 3) << 3) | (((mloc >> 4) & 1) << 2);
#pragma unroll
        for (int j = 0; j < 3; ++j) {
            const int colg = colgj[j];
            const float bv = bvj[j];
            if (colg >= 2048) {
                // V: write transposed VT[(b*8+h)*128 + l][mperm]; accumulate vsum partial
                const int hh = (colg - 2048) >> 7, ll = (colg - 2048) & 127;
                bf16x4 sv;
#pragma unroll
                for (int r = 0; r < 4; ++r) { sv[r] = (bf16_t)(acc[i][j][r] + bv); ps[j] += acc[i][j][r]; }
                *(bf16x4*)(vtOut + ((size_t)(bb2 * 8 + hh) * 128 + ll) * (size_t)N_ + mperm) = sv;
            } else {
                const float qs = (colg < 1024) ? 0.08838834764831845f : 1.f;   // pre-scale q by 1/sqrt(A)
#pragma unroll
                for (int r = 0; r < 4; ++r)
                    outQK[(size_t)(rowg + r) * QKN_ + colg] = (bf16_t)((acc[i][j][r] + bv) * qs);
            }
        }
    }
#pragma unroll
    for (int j = 0; j < 3; ++j) {
        const int colg = colgj[j];
        if (colg >= 2048) {
            const int hh = (colg - 2048) >> 7, ll = (colg - 2048) & 127;
            float p = ps[j] + 32.f * bvj[j];   // this lane covered 32 rows
            p += __shfl_xor(p, 16);
            p += __shfl_xor(p, 32);
            if (quad == 0) atomicAdd(&vsOut[(size_t)(bb2 * 8 + hh) * 128 + ll], p);
        }
    }
}

// ---------------- out-proj GEMM (unchanged control): 256x128 tile, ring-4, single barrier/K-step ----------------
// Grid 8x32 = 256 blocks = exactly 1 generation. x_out = resid_in + A@W + bias.
__global__ __launch_bounds__(512, 2) void gemm_out(const bf16_t* __restrict__ Am, const bf16_t* __restrict__ Bt,
                                                   const float* __restrict__ bias,
                                                   const float* __restrict__ resid_in, float* __restrict__ resid_out)
{
    __shared__ bf16_t As[4 * 256 * 32];
    __shared__ bf16_t Bs[4 * 128 * 32];
    const int tid = threadIdx.x;
    const int lane = tid & 63, wave = tid >> 6;
    const int wr = wave >> 2, wc = wave & 3;
    const int quad = lane >> 4, l15 = lane & 15;
    const int swz = quad ^ ((l15 >> 1) & 3);
    const int slane8 = ((lane & 3) ^ ((lane >> 3) & 3)) * 8;
    const int lrow = lane >> 2;
    const int m0 = blockIdx.y * 256, n0 = blockIdx.x * 128;
    const int Kn = D_;

    const int chA0 = wave * 2, chA1 = chA0 + 1;
    const bf16_t* gA0 = Am + (size_t)(m0 + chA0 * 16 + lrow) * Kn + slane8;
    const bf16_t* gA1 = Am + (size_t)(m0 + chA1 * 16 + lrow) * Kn + slane8;
    const bf16_t* gB  = Bt + (size_t)(n0 + wave * 16 + lrow) * Kn + slane8;
    bf16_t* const dA0 = &As[chA0 * 512 + lane * 8];
    bf16_t* const dA1 = &As[chA1 * 512 + lane * 8];
    bf16_t* const dB  = &Bs[wave * 512 + lane * 8];

    auto STAGE = [&](int slot) {
        async_copy16(gA0, dA0 + slot * 8192);
        async_copy16(gA1, dA1 + slot * 8192);
        async_copy16(gB,  dB  + slot * 4096);
        gA0 += 32; gA1 += 32; gB += 32;
    };

    f32x4 acc[8][2] = {};
    const int NT = Kn >> 5;

    STAGE(0); STAGE(1); STAGE(2);
    asm volatile("s_waitcnt vmcnt(6)" ::: "memory");
    __builtin_amdgcn_s_barrier();

    const int aoff = (wr * 128 + l15) * 32 + swz * 8;
    const int boff = (wc * 32  + l15) * 32 + swz * 8;

    for (int t = 0; t < NT; ++t) {
        const int ring = t & 3;
        const bf16_t* ra = &As[ring * 8192 + aoff];
        const bf16_t* rb = &Bs[ring * 4096 + boff];
        bf16x8 af[8], bfv[2];
#pragma unroll
        for (int j = 0; j < 2; ++j) bfv[j] = *(const bf16x8*)(rb + j * 512);
#pragma unroll
        for (int i = 0; i < 8; ++i) af[i] = *(const bf16x8*)(ra + i * 512);
        if (t + 3 < NT) STAGE((t + 3) & 3);
        __builtin_amdgcn_s_setprio(1);
#pragma unroll
        for (int i = 0; i < 8; ++i)
#pragma unroll
            for (int j = 0; j < 2; ++j)
                acc[i][j] = __builtin_amdgcn_mfma_f32_16x16x32_bf16(af[i], bfv[j], acc[i][j], 0, 0, 0);
        __builtin_amdgcn_s_setprio(0);
        if (t + 3 < NT)      asm volatile("s_waitcnt vmcnt(6)" ::: "memory");
        else if (t + 2 < NT) asm volatile("s_waitcnt vmcnt(3)" ::: "memory");
        else if (t + 1 < NT) asm volatile("s_waitcnt vmcnt(0)" ::: "memory");
        __builtin_amdgcn_s_barrier();
    }

#pragma unroll
    for (int i = 0; i < 8; ++i) {
#pragma unroll
        for (int j = 0; j < 2; ++j) {
            const int colg = n0 + wc * 32 + j * 16 + l15;
            const float bv = bias[colg];
#pragma unroll
            for (int r = 0; r < 4; ++r) {
                const int rowg = m0 + wr * 128 + i * 16 + quad * 4 + r;
                const size_t off = (size_t)rowg * D_ + colg;
                resid_out[off] = resid_in[off] + acc[i][j][r] + bv;
            }
        }
    }
}

// ---------------- fused masked-silu-softmax attention (unchanged) ----------------
template<bool CAUSAL>
__device__ __forceinline__ void attn_tile(
    int m0, int m0n, int n0, int b, int h,
    const bf16_t* __restrict__ qk, const bf16_t* __restrict__ vtb,
    const unsigned short* __restrict__ maskB,
    bf16_t* Ks, bf16_t* Vs,
    const bf16x8 (&qf)[2][4], bf16x8 onesf,
    f32x4 (&oacc)[2][8], f32x4 (&dacc)[2])
{
    const int tid = threadIdx.x, lane = tid & 63, wave = tid >> 6;
    const int quad = lane >> 4, l15 = lane & 15;
    const int swz = quad ^ ((l15 >> 1) & 3);
    const int slane8 = ((lane & 3) ^ ((lane >> 3) & 3)) * 8;
    const int lrow = lane >> 2;
    const float invN = 1.f / 2048.f;

    // (1) issue V(m0) -> Vs ; AND-mask fragments (L2-resident 16KB) issued alongside
#pragma unroll
    for (int s = 0; s < 8; ++s) {
        const int kkc = s & 3, rg = (s >> 2) + wave * 2;
        async_copy16(vtb + (size_t)(rg * 16 + lrow) * N_ + m0 + kkc * 32 + slane8,
                     &Vs[kkc * 4096 + rg * 512 + lane * 8]);
    }
    bf16x8 mAf[4];
#pragma unroll
    for (int kk = 0; kk < 4; ++kk)
        mAf[kk] = *(const bf16x8*)(maskB + m0 + kk * 32 + quad * 8);

    // (2) S^T = K Q^T
    f32x4 sacc[2][8] = {};
    __builtin_amdgcn_s_setprio(1);
#pragma unroll
    for (int kk = 0; kk < 4; ++kk) {
#pragma unroll
        for (int j = 0; j < 8; ++j) {
            bf16x8 kf = *(const bf16x8*)&Ks[kk * 4096 + (j * 16 + l15) * 32 + swz * 8];
            sacc[0][j] = __builtin_amdgcn_mfma_f32_16x16x32_bf16(kf, qf[0][kk], sacc[0][j], 0, 0, 0);
            sacc[1][j] = __builtin_amdgcn_mfma_f32_16x16x32_bf16(kf, qf[1][kk], sacc[1][j], 0, 0, 0);
        }
    }
    __builtin_amdgcn_s_setprio(0);

    // (3) softmax -> pf A-frags in registers; e = 1 + silu(s)/N, masked via AND
    bf16x8 pf[2][4];
#pragma unroll
    for (int kk = 0; kk < 4; ++kk) {
#pragma unroll
        for (int s = 0; s < 2; ++s) {
            const int j = kk * 2 + s;
#pragma unroll
            for (int nb = 0; nb < 2; ++nb) {
#pragma unroll
                for (int r = 0; r < 4; ++r) {
                    const float sv = sacc[nb][j][r];                      // already scaled by 1/sqrt(A)
                    const float xc = __builtin_amdgcn_fmed3f(sv, -4.f, 4.f);
                    float sg = __builtin_fmaf(xc, 0.25f * invN, 0.5f * invN);
                    sg = __builtin_fmaf(-(xc * (0.03125f * invN)), fabsf(xc), sg);
                    float e = __builtin_fmaf(sv, sg, 1.f);
                    if (CAUSAL) {
                        const int dmn = (m0 + j * 16 + quad * 4 + r) - (n0 + wave * 32 + nb * 16 + l15);
                        e = (dmn > 0) ? e : 0.f;
                    }
                    pf[nb][kk][s * 4 + r] = (bf16_t)e;
                }
            }
        }
        *(u32x4*)&pf[0][kk] = *(u32x4*)&pf[0][kk] & *(const u32x4*)&mAf[kk];
        *(u32x4*)&pf[1][kk] = *(u32x4*)&pf[1][kk] & *(const u32x4*)&mAf[kk];
    }

    __syncthreads();   // V landed + visible; Ks free

    // (4) prefetch K(m0n) -> Ks
    if (m0n < N_) {
        const size_t baseq = (size_t)b * N_ * QKN_;
#pragma unroll
        for (int s = 0; s < 8; ++s) {
            const int kkc = s & 3, rg = (s >> 2) + wave * 2;
            async_copy16(qk + baseq + (size_t)(m0n + rg * 16 + lrow) * QKN_ + 1024 + h * 128 + kkc * 32 + slane8,
                         &Ks[kkc * 4096 + rg * 512 + lane * 8]);
        }
    }

    // (5) O += P V ; den += P ones  (pf already masked -> den correct)
    __builtin_amdgcn_s_setprio(1);
#pragma unroll
    for (int kk = 0; kk < 4; ++kk) {
        dacc[0] = __builtin_amdgcn_mfma_f32_16x16x32_bf16(pf[0][kk], onesf, dacc[0], 0, 0, 0);
        dacc[1] = __builtin_amdgcn_mfma_f32_16x16x32_bf16(pf[1][kk], onesf, dacc[1], 0, 0, 0);
#pragma unroll
        for (int j = 0; j < 8; ++j) {
            bf16x8 vf = *(const bf16x8*)&Vs[kk * 4096 + (j * 16 + l15) * 32 + swz * 8];
            oacc[0][j] = __builtin_amdgcn_mfma_f32_16x16x32_bf16(pf[0][kk], vf, oacc[0][j], 0, 0, 0);
            oacc[1][j] = __builtin_amdgcn_mfma_f32_16x16x32_bf16(pf[1][kk], vf, oacc[1][j], 0, 0, 0);
        }
    }
    __builtin_amdgcn_s_setprio(0);
    __syncthreads();   // K(m0n) landed + visible; Vs free
}

__global__ __launch_bounds__(256, 2) void attn_kernel(const bf16_t* __restrict__ qk, const bf16_t* __restrict__ vt,
                                                      const int* __restrict__ past_ids, const float* __restrict__ vsum,
                                                      const unsigned short* __restrict__ maskA,
                                                      bf16_t* __restrict__ att)
{
    __shared__ bf16_t Ks[4 * 128 * 32];
    __shared__ bf16_t Vs[4 * 128 * 32];

    const int bx = blockIdx.x;
    const int bh = bx & 31, g = bx >> 5;
    const int t = (g < 8) ? g : 23 - g;          // CU co-resident pair (g,g+8) -> tiles sum 17
    const int b = bh >> 3, h = bh & 7;
    const int n0 = t << 7;
    const int tid = threadIdx.x, lane = tid & 63, wave = tid >> 6;
    const int quad = lane >> 4, l15 = lane & 15;
    const int slane8 = ((lane & 3) ^ ((lane >> 3) & 3)) * 8;
    const int lrow = lane >> 2;
    const bf16_t* vtb = vt + (size_t)bh * 128 * N_;
    const unsigned short* maskB = maskA + b * N_;
    const float invN = 1.f / 2048.f;

    // Q B-frags resident in VGPRs (2 n16-blocks per wave)
    bf16x8 qf[2][4];
#pragma unroll
    for (int nb = 0; nb < 2; ++nb) {
        const bf16_t* gq = qk + (size_t)b * N_ * QKN_ + (size_t)(n0 + wave * 32 + nb * 16 + l15) * QKN_ + h * 128 + quad * 8;
#pragma unroll
        for (int kk = 0; kk < 4; ++kk) qf[nb][kk] = *(const bf16x8*)(gq + kk * 32);
    }
    const float vnf0 = past_ids[b * N_ + n0 + wave * 32 + l15] != 0 ? 1.f : 0.f;
    const float vnf1 = past_ids[b * N_ + n0 + wave * 32 + 16 + l15] != 0 ? 1.f : 0.f;
    bf16x8 onesf;
#pragma unroll
    for (int i = 0; i < 8; ++i) onesf[i] = (bf16_t)1.f;

    // prologue: stage K(first tile)
    {
        const size_t baseq = (size_t)b * N_ * QKN_;
#pragma unroll
        for (int s = 0; s < 8; ++s) {
            const int kkc = s & 3, rg = (s >> 2) + wave * 2;
            async_copy16(qk + baseq + (size_t)(n0 + rg * 16 + lrow) * QKN_ + 1024 + h * 128 + kkc * 32 + slane8,
                         &Ks[kkc * 4096 + rg * 512 + lane * 8]);
        }
    }
    __syncthreads();

    f32x4 oacc[2][8] = {};
    f32x4 dacc[2] = {};

    attn_tile<true>(n0, n0 + 128, n0, b, h, qk, vtb, maskB, Ks, Vs, qf, onesf, oacc, dacc);
    for (int m0 = n0 + 128; m0 < N_; m0 += 128)
        attn_tile<false>(m0, m0 + 128, n0, b, h, qk, vtb, maskB, Ks, Vs, qf, onesf, oacc, dacc);

    // epilogue: rows n = quad*4+r (+nb*16), cols j*16+l15 ; invalid n or empty den -> uniform mean(V)
    float vsr[8];
#pragma unroll
    for (int j = 0; j < 8; ++j) vsr[j] = vsum[bh * 128 + j * 16 + l15];
#pragma unroll
    for (int nb = 0; nb < 2; ++nb) {
        const float vn = nb ? vnf1 : vnf0;
#pragma unroll
        for (int r = 0; r < 4; ++r) {
            const float dn = dacc[nb][r];
            const bool uni = (vn == 0.f) || !(dn > 0.f);
            const float rc = uni ? 0.f : __builtin_amdgcn_rcpf(dn);
            const int gn = n0 + wave * 32 + nb * 16 + quad * 4 + r;
#pragma unroll
            for (int j = 0; j < 8; ++j) {
                const float ov = uni ? (vsr[j] * invN) : (oacc[nb][j][r] * rc);
                att[(size_t)(b * N_ + gn) * 1024 + h * 128 + j * 16 + l15] = (bf16_t)ov;
            }
        }
    }
}

extern "C" void kernel_launch(void* const* d_in, const int* in_sizes, int n_in,
                              void* d_out, int out_size, void* d_ws, size_t ws_size,
                              hipStream_t stream) {
    (void)in_sizes; (void)n_in; (void)out_size; (void)ws_size;
    const int*   past_ids = (const int*)d_in[1];
    const float* past_emb = (const float*)d_in[2];
    const float* qkv_w    = (const float*)d_in[3];
    const float* qkv_b    = (const float*)d_in[4];
    const float* out_w    = (const float*)d_in[5];
    const float* out_b    = (const float*)d_in[6];
    const float* ln_g     = (const float*)d_in[7];
    const float* ln_b     = (const float*)d_in[8];

    float* x = (float*)d_out;
    char* ws = (char*)d_ws;
    bf16_t* WT  = (bf16_t*)(ws + WT_OFF);
    bf16_t* OWT = (bf16_t*)(ws + OWT_OFF);
    bf16_t* XN  = (bf16_t*)(ws + XN_OFF);
    bf16_t* QK  = (bf16_t*)(ws + QK_OFF);
    bf16_t* VT  = (bf16_t*)(ws + VT_OFF);
    bf16_t* ATT = (bf16_t*)(ws + ATT_OFF);
    float*  QBR = (float*)(ws + QBR_OFF);
    float*  VSL = (float*)(ws + VS_OFF);
    unsigned short* MASKA = (unsigned short*)(ws + MASK_OFF);

    repack_qkvw<<<dim3(48, 16, NB_), dim3(64, 4), 0, stream>>>(qkv_w, WT);
    repack_outw<<<dim3(16, 16, NB_), dim3(64, 4), 0, stream>>>(out_w, OWT);
    repack_qb<<<48, 256, 0, stream>>>(qkv_b, QBR);
    mask_kernel<<<32, 256, 0, stream>>>(past_ids, MASKA, VSL);

    for (int layer = 0; layer < NB_; ++layer) {
        const float* xin = (layer == 0) ? past_emb : x;
        ln_kernel<<<M_, 256, 0, stream>>>(xin, ln_g + layer * D_, ln_b + layer * D_, XN);
        gemm_qkv<<<dim3(QN_ / 192, M_ / 256), 512, 0, stream>>>(
            XN, WT + (size_t)layer * QN_ * D_, QBR + layer * QN_, QK, VT, VSL + layer * 4096);
        attn_kernel<<<512, 256, 0, stream>>>(QK, VT, past_ids, VSL + layer * 4096, MASKA, ATT);
        gemm_out<<<dim3(D_ / 128, M_ / 256), 512, 0, stream>>>(
            ATT, OWT + (size_t)layer * D_ * D_, out_b + layer * D_, xin, x);
    }
}